// Round 9
// baseline (5910.072 us; speedup 1.0000x reference)
//
#include <hip/hip_runtime.h>
#include <stdint.h>
#include <stddef.h>

#define T_   1024
#define BATCH 128
#define IN    512
#define HID  1024
#define OUTN  256

typedef unsigned short u16;
typedef __attribute__((ext_vector_type(8))) short short8;
typedef __attribute__((ext_vector_type(4))) float floatx4;

// Device-global scratch (d_ws size unknown). Fully rewritten every call.
__device__ u16 g_xbf[(size_t)BATCH * T_ * IN];     // x in bf16 [B*T][IN]
__device__ u16 g_kT[(size_t)HID * IN];             // kernel^T bf16 [H][IN]
// xp in chunk-fragment layout [T][8 bt][16 jt][1024]:
//   chunk idx = (j*4+rr)*64 + lp  <->  (row r=(lp>>4)*4+rr, col c=j*16+(lp&15))
__device__ u16 g_xp[(size_t)T_ * 8 * 16 * 1024];
// h ping-pong, chunk-fragment layout: [2][8 bt][16 jt][1024]
__device__ u16 g_h[(size_t)2 * 8 * 16 * 1024];
// PER-WAVE FLAG BLOCK: per bt, 64 contiguous words (word jt*4+w = last step
// published by wave w of WG(bt,jt)). Parallel word stores only (r6 lesson:
// same-line RMW chains cost 2x). Consumer wave w polls ONLY words
// [16w,16w+16) = its 4 producer WGs x 4 waves -> one coalesced 64B load.
__device__ unsigned g_sync[8][128];

__device__ __forceinline__ u16 f2bf(float f) {
    uint32_t u = __builtin_bit_cast(uint32_t, f);
    u += 0x7fffu + ((u >> 16) & 1u);          // round-to-nearest-even
    return (u16)(u >> 16);
}
__device__ __forceinline__ float bf2f(u16 s) {
    uint32_t u = ((uint32_t)s) << 16;
    return __builtin_bit_cast(float, u);
}

__global__ void k_init() {
    for (int i = threadIdx.x; i < 8 * 128; i += blockDim.x)
        ((unsigned*)g_sync)[i] = 0u;
}

// Convert x -> bf16 and kernel -> bf16 transposed (kT[n][k])
__global__ __launch_bounds__(256) void k_convert(const float* __restrict__ x,
                                                 const float* __restrict__ kern) {
    size_t i = (size_t)blockIdx.x * blockDim.x + threadIdx.x;
    size_t stride = (size_t)gridDim.x * blockDim.x;
    size_t n4 = (size_t)BATCH * T_ * IN / 4;
    for (size_t p = i; p < n4; p += stride) {
        float4 v = ((const float4*)x)[p];
        ushort4 o;
        o.x = f2bf(v.x); o.y = f2bf(v.y); o.z = f2bf(v.z); o.w = f2bf(v.w);
        ((ushort4*)g_xbf)[p] = o;
    }
    for (size_t p = i; p < (size_t)IN * HID; p += stride) {
        size_t k = p >> 10, n = p & 1023;        // read coalesced over n
        g_kT[n * IN + k] = f2bf(kern[p]);
    }
}

// xp = x @ kernel + bias   (M=131072, N=1024, K=512), bf16 MFMA, 128x128 tile.
__global__ __launch_bounds__(256) void k_xp(const float* __restrict__ bias) {
    __shared__ u16 As[128][40];   // +8 pad: 2-way-only bank aliasing on b128 reads
    __shared__ u16 Bs[128][40];
    const int tid = threadIdx.x;
    const int bx = blockIdx.x & 7;       // n tile (8)
    const int by = blockIdx.x >> 3;      // m tile (1024)
    const int m0 = by * 128, n0 = bx * 128;
    const int lane = tid & 63, wave = tid >> 6;
    const int m_off = (wave & 1) * 64, n_off = (wave >> 1) * 64;
    const int sr = tid >> 1, skh = (tid & 1) * 16;

    floatx4 acc[4][4] = {};
    for (int k0 = 0; k0 < IN; k0 += 32) {
        const u16* ga = g_xbf + (size_t)(m0 + sr) * IN + k0 + skh;
        const u16* gb = g_kT  + (size_t)(n0 + sr) * IN + k0 + skh;
        int4 a0 = *(const int4*)ga, a1 = *(const int4*)(ga + 8);
        int4 b0 = *(const int4*)gb, b1 = *(const int4*)(gb + 8);
        __syncthreads();
        *(int4*)&As[sr][skh] = a0; *(int4*)&As[sr][skh + 8] = a1;
        *(int4*)&Bs[sr][skh] = b0; *(int4*)&Bs[sr][skh + 8] = b1;
        __syncthreads();
        short8 af[4], bf[4];
#pragma unroll
        for (int i = 0; i < 4; i++)
            af[i] = *(const short8*)&As[m_off + i * 16 + (lane & 15)][(lane >> 4) * 8];
#pragma unroll
        for (int j = 0; j < 4; j++)
            bf[j] = *(const short8*)&Bs[n_off + j * 16 + (lane & 15)][(lane >> 4) * 8];
#pragma unroll
        for (int i = 0; i < 4; i++)
#pragma unroll
            for (int j = 0; j < 4; j++)
                acc[i][j] = __builtin_amdgcn_mfma_f32_16x16x32_bf16(af[i], bf[j], acc[i][j], 0, 0, 0);
    }
    // D layout: col = lane&15, row = (lane>>4)*4 + reg  [m89-verified]
#pragma unroll
    for (int j = 0; j < 4; j++) {
        int n = n0 + n_off + j * 16 + (lane & 15);
        float bv = bias[n];
        int jt_x = n >> 6;
        int jx4 = ((n >> 4) & 3) * 4;
        int c15 = n & 15;
#pragma unroll
        for (int i = 0; i < 4; i++) {
#pragma unroll
            for (int rr = 0; rr < 4; rr++) {
                int m = m0 + m_off + i * 16 + (lane >> 4) * 4 + rr;
                int b = m >> 10, t = m & 1023;
                int r = b & 15;
                size_t idx = (((size_t)t * 8 + (b >> 4)) * 16 + jt_x) * 1024
                           + (size_t)((jx4 + (r & 3)) * 64 + (r >> 2) * 16 + c15);
                g_xp[idx] = f2bf(acc[i][j][rr] + bv);
            }
        }
    }
}

// Persistent scan: 128 WGs = 8 bt-groups (16 rows) x 16 jt-chunks (64 cols).
// DATAFLOW PARTIAL-WAIT fabric, proven-cost primitives ONLY (r8 lesson: no
// compiler-lowered agent RELEASE on the hot path -> it can emit buffer_wbl2):
//  - publish: all lanes' h-stores (agent relaxed, write-through) ->
//    inline-asm s_waitcnt vmcnt(0) (wave-wide drain, == what r6's barrier
//    provided) -> lane-0 RELAXED flag store. h visible in L3 before flag.
//  - wait: wave w polls only words [16w,16w+16) (its 4 producer WGs x 4
//    waves), one coalesced 64B line + s_sleep(1) backoff (r6-proven body).
//    Waves start MFMA independently; straggler jitter hides under sibling
//    waves' MFMA -> step pays max-of-4 per wave, not max-of-16 up front.
//  - 2-buffer safety: the red-exchange __syncthreads joins the 4 partial
//    waits (4x16 = all 64 flags >= t observed) before ANY h_{t+1} store,
//    i.e. every WG finished its step-t reads of h_{t-1}. Same invariant as r6.
#define SCAN_LDS (64 * 1032 * 2 + 4 * 4 * 4 * 64 * 4)
__global__ __launch_bounds__(256, 1) void k_scan(const float* __restrict__ R) {
    extern __shared__ char smem[];
    u16* Rs = (u16*)smem;                          // [64][1032] (k-pad 8 -> 2-way banks)
    float* red = (float*)(smem + 64 * 1032 * 2);   // [src][j][rr][64] cross-wave partials
    const int tid = threadIdx.x, lane = tid & 63, w = tid >> 6;
    const int g = blockIdx.x, bt = g & 7, jt = g >> 3;
    const int n0 = jt * 64;

    // Load R columns n0..n0+63 into LDS as Rs[n_local][k]
    {
        const int rrow = tid >> 4;
        const int c4 = (tid & 15) * 4;
        for (int k = rrow; k < HID; k += 16) {
            float4 v = *(const float4*)&R[(size_t)k * HID + n0 + c4];
            Rs[(size_t)(c4 + 0) * 1032 + k] = f2bf(v.x);
            Rs[(size_t)(c4 + 1) * 1032 + k] = f2bf(v.y);
            Rs[(size_t)(c4 + 2) * 1032 + k] = f2bf(v.z);
            Rs[(size_t)(c4 + 3) * 1032 + k] = f2bf(v.w);
        }
    }
    __syncthreads();

    const int hi = lane >> 4;
    // consumer chunk offset (u16 units); add s*512 for k-substep s
    const int coff = (lane >> 5) * 256 + (lane & 3) * 64
                   + ((lane & 15) >> 2) * 16 + (hi & 1) * 8;
    // wave w's producers: WGs 4w..4w+3, all 4 waves each -> words 16w..16w+15
    const unsigned* pline = &g_sync[bt][16 * w + (lane & 15)];
    unsigned* myflag = &g_sync[bt][jt * 4 + w];

    long bail = 0;
    for (int t = 0; t < T_; ++t) {
        // xp prefetch (4 coalesced 128B wave-loads; latency hides under the poll)
        const u16* xpb = g_xp + ((((size_t)t * 8 + bt) * 16 + jt) << 10) + w * 256 + lane;
        u16 xr0 = xpb[0], xr1 = xpb[64], xr2 = xpb[128], xr3 = xpb[192];

        floatx4 acc[4] = {};
        if (t > 0) {
            const unsigned tgt = (unsigned)t;
            unsigned v = __hip_atomic_load(pline, __ATOMIC_RELAXED, __HIP_MEMORY_SCOPE_AGENT);
            while (!__all((int)(v >= tgt))) {
                __builtin_amdgcn_s_sleep(1);
                v = __hip_atomic_load(pline, __ATOMIC_RELAXED, __HIP_MEMORY_SCOPE_AGENT);
                if (++bail > (1L << 22)) break;   // fuse (never hit if co-resident)
            }
            const u16* hb = g_h + ((size_t)(t & 1) * 8 + bt) * 16384;
            union { unsigned long long u[2]; short8 v; } af[4][2];
            // K-split: wave w covers k in [w*256, w*256+256); 8x16B frags up-front
#pragma unroll
            for (int cc = 0; cc < 4; ++cc) {
                const u16* cb = hb + (size_t)(4 * w + cc) * 1024 + coff;
#pragma unroll
                for (int s = 0; s < 2; ++s) {
                    const unsigned long long* q = (const unsigned long long*)(cb + s * 512);
                    af[cc][s].u[0] = __hip_atomic_load(q,     __ATOMIC_RELAXED, __HIP_MEMORY_SCOPE_AGENT);
                    af[cc][s].u[1] = __hip_atomic_load(q + 1, __ATOMIC_RELAXED, __HIP_MEMORY_SCOPE_AGENT);
                }
            }
#pragma unroll
            for (int cc = 0; cc < 4; ++cc)
#pragma unroll
                for (int s = 0; s < 2; ++s) {
                    const int kg = (4 * w + cc) * 64 + s * 32 + hi * 8;
#pragma unroll
                    for (int jj = 0; jj < 4; ++jj) {
                        short8 bfr = *(const short8*)&Rs[(size_t)(jj * 16 + (lane & 15)) * 1032 + kg];
                        acc[jj] = __builtin_amdgcn_mfma_f32_16x16x32_bf16(af[cc][s].v, bfr, acc[jj], 0, 0, 0);
                    }
                }
        }
        // cross-wave partial exchange (static indexing only; rule #20)
#pragma unroll
        for (int jj = 0; jj < 4; ++jj)
#pragma unroll
            for (int rr = 0; rr < 4; ++rr)
                red[((w * 4 + jj) * 4 + rr) * 64 + lane] = acc[jj][rr];
        __syncthreads();   // joins the 4 partial waits: all 64 flags >= t observed
        // wave w reduces + activates + stores col-group j=w of own chunk
        u16* ob = g_h + ((size_t)((t + 1) & 1) * 8 + bt) * 16384
                + (size_t)jt * 1024 + w * 256 + lane;
        const float xf[4] = { bf2f(xr0), bf2f(xr1), bf2f(xr2), bf2f(xr3) };
#pragma unroll
        for (int rr = 0; rr < 4; ++rr) {
            float s = xf[rr];
#pragma unroll
            for (int src = 0; src < 4; ++src)
                s += red[((src * 4 + w) * 4 + rr) * 64 + lane];
            s = fminf(fmaxf(s, -9.0f), 9.0f);
            float e = __expf(2.0f * s);                       // tanh = (e^2x-1)/(e^2x+1)
            float hv = (e - 1.0f) * __builtin_amdgcn_rcpf(e + 1.0f);
            __hip_atomic_store(ob + rr * 64, f2bf(hv),
                               __ATOMIC_RELAXED, __HIP_MEMORY_SCOPE_AGENT);
        }
        // per-wave publish: wave-wide vmcnt drain (covers all 64 lanes' h-stores,
        // exactly what r6's __syncthreads provided) then RELAXED flag store.
        asm volatile("s_waitcnt vmcnt(0)" ::: "memory");
        if (lane == 0)
            __hip_atomic_store(myflag, (unsigned)(t + 1),
                               __ATOMIC_RELAXED, __HIP_MEMORY_SCOPE_AGENT);
        __syncthreads();   // protects red reuse next iteration
    }
}

// out = h_last @ fc_w + fc_b   (128 x 256); h_1024 is in buffer 0 (1024&1==0)
__global__ __launch_bounds__(256) void k_final(const float* __restrict__ fcw,
                                               const float* __restrict__ fcb,
                                               float* __restrict__ out) {
    __shared__ float hsh[HID];
    int b = blockIdx.x, o = threadIdx.x;
    int bt = b >> 4, r = b & 15;
    const u16* hb = g_h + (size_t)bt * 16384;
    for (int k = o; k < HID; k += 256) {
        int q = k >> 6, c = k & 63;
        int idx = q * 1024 + ((c >> 4) * 4 + (r & 3)) * 64 + (r >> 2) * 16 + (c & 15);
        hsh[k] = bf2f(__hip_atomic_load(hb + idx, __ATOMIC_RELAXED, __HIP_MEMORY_SCOPE_AGENT));
    }
    __syncthreads();
    float acc = fcb[o];
#pragma unroll 8
    for (int k = 0; k < HID; k++)
        acc += hsh[k] * fcw[(size_t)k * OUTN + o];
    out[(size_t)b * OUTN + o] = acc;
}

extern "C" void kernel_launch(void* const* d_in, const int* in_sizes, int n_in,
                              void* d_out, int out_size, void* d_ws, size_t ws_size,
                              hipStream_t stream) {
    const float* x    = (const float*)d_in[0];
    const float* kern = (const float*)d_in[1];
    const float* R    = (const float*)d_in[2];
    const float* bias = (const float*)d_in[3];
    const float* fcw  = (const float*)d_in[4];
    const float* fcb  = (const float*)d_in[5];
    float* out = (float*)d_out;

    k_init<<<1, 256, 0, stream>>>();
    k_convert<<<4096, 256, 0, stream>>>(x, kern);
    k_xp<<<8192, 256, 0, stream>>>(bias);
    (void)hipFuncSetAttribute((const void*)k_scan,
                              hipFuncAttributeMaxDynamicSharedMemorySize, SCAN_LDS);
    k_scan<<<128, 256, SCAN_LDS, stream>>>(R);
    k_final<<<128, 256, 0, stream>>>(fcw, fcb, out);
}